// Round 7
// baseline (222.043 us; speedup 1.0000x reference)
//
#include <hip/hip_runtime.h>

// Problem constants (from setup_inputs): B=4, S=8, T=2048, R=256
#define T_N 2048
#define R_N 256
#define SLICES 32                     // B*S
#define NELEM (SLICES * T_N * R_N)    // 16,777,216 per tensor
#define INFV 3.0e38f
#define MIN_BLOCKS 2048               // 2048 x 256 threads, 8 float4/tensor/thread
#define MIN_THREADS (MIN_BLOCKS * 256)
#define LSTR 2056                     // list stride: 2048 + 8 sentinel slots (16B-aligned)

// Deep-ILP streaming min (unchanged from R6: ~25us, HBM-bound).
__global__ __launch_bounds__(256) void kmin(const float* __restrict__ x,
                                            const float* __restrict__ y,
                                            float* __restrict__ partial,
                                            float* __restrict__ out) {
    if (blockIdx.x == 0 && threadIdx.x < 4) out[threadIdx.x] = 0.0f;
    const int g0 = blockIdx.x * 256 + threadIdx.x;   // 0..524287
    const float4* __restrict__ x4 = (const float4*)x;
    const float4* __restrict__ y4 = (const float4*)y;
    float m0 = INFV, m1 = INFV;
    #pragma unroll
    for (int half = 0; half < 2; ++half) {
        float4 va[4], vb[4];
        #pragma unroll
        for (int it = 0; it < 4; ++it) {
            const int idx = g0 + (half * 4 + it) * MIN_THREADS;
            va[it] = x4[idx];
            vb[it] = y4[idx];
        }
        #pragma unroll
        for (int it = 0; it < 4; ++it) {
            m0 = fminf(m0, fminf(fminf(va[it].x, va[it].y), fminf(va[it].z, va[it].w)));
            m1 = fminf(m1, fminf(fminf(vb[it].x, vb[it].y), fminf(vb[it].z, vb[it].w)));
        }
    }
    float m = fminf(m0, m1);
    #pragma unroll
    for (int off = 32; off; off >>= 1) m = fminf(m, __shfl_down(m, off));
    __shared__ float sm[4];
    if ((threadIdx.x & 63) == 0) sm[threadIdx.x >> 6] = m;
    __syncthreads();
    if (threadIdx.x == 0)
        partial[blockIdx.x] = fminf(fminf(sm[0], sm[1]), fminf(sm[2], sm[3]));
}

// 1024-thread block = 4 problems, 4 waves/problem, 2 merge segments/lane.
// Latency-bound fixes: interleaved A/B segments (2x ILP on corank + merge
// chains), sentinel-padded lists (no bounds selects), branchless corank.
__global__ __launch_bounds__(1024, 8) void kmain(const float* __restrict__ x,
                                                 const float* __restrict__ y,
                                                 const float* __restrict__ partial,
                                                 float* __restrict__ out) {
    __shared__ float L[8 * LSTR];     // problem p: U at (2p)*LSTR, V at (2p+1)*LSTR
    __shared__ float red16[16];
    __shared__ float psum[4][2][4];   // [problem][list][wave-chunk] scan partials
    __shared__ float pacc[4][4];      // [problem][wave] result partials

    const int tid = threadIdx.x;
    const int w = tid >> 6;           // wave 0..15
    const int lane = tid & 63;

    // ---- phase 0: global min (partial[2048], two elements per thread) ----
    {
        float m = fminf(partial[tid], partial[tid + 1024]);
        #pragma unroll
        for (int off = 32; off; off >>= 1) m = fminf(m, __shfl_down(m, off));
        if (lane == 0) red16[w] = m;
    }
    __syncthreads();
    float mn = red16[0];
    #pragma unroll
    for (int k = 1; k < 16; ++k) mn = fminf(mn, red16[k]);
    const float sh = 1.1f * fminf(mn, 0.0f);

    // ---- XCD-aware remap: 4 blocks sharing a 64B global line -> same XCD ----
    const int blk = blockIdx.x;
    const int xcd = blk & 7;
    const int k2 = blk >> 3;
    const int sub = k2 & 3;
    const int rest = k2 >> 2;
    const int rt = (((rest & 1) << 3) + xcd) * 4 + sub;   // 0..63
    const int bs = rest >> 1;                              // 0..31
    const size_t base = (size_t)bs * (T_N * R_N) + (size_t)(rt * 4);

    // ---- sentinels: 8 pads per list = INF ----
    if (tid < 64) L[(tid >> 3) * LSTR + T_N + (tid & 7)] = INFV;

    // ---- staging: 4 columns of x and y (shifted) into sentinel-padded LDS ----
    #pragma unroll
    for (int it = 0; it < 2; ++it) {
        const int t = tid + 1024 * it;
        const float4 a = *(const float4*)(x + base + (size_t)t * R_N);
        const float4 b = *(const float4*)(y + base + (size_t)t * R_N);
        L[0 * LSTR + t] = a.x - sh;  L[2 * LSTR + t] = a.y - sh;
        L[4 * LSTR + t] = a.z - sh;  L[6 * LSTR + t] = a.w - sh;
        L[1 * LSTR + t] = b.x - sh;  L[3 * LSTR + t] = b.y - sh;
        L[5 * LSTR + t] = b.z - sh;  L[7 * LSTR + t] = b.w - sh;
    }
    __syncthreads();

    const int p  = w >> 2;            // problem 0..3
    const int wl = w & 3;             // wave within problem
    const int pl = (wl << 6) | lane;  // problem-lane 0..255
    float* __restrict__ cu = &L[(2 * p) * LSTR];
    float* __restrict__ cv = &L[(2 * p + 1) * LSTR];

    // ---- scan: lane owns elems [8*pl, 8*pl+8) = quads 2pl, 2pl+1 ----
    {
        float4* __restrict__ cu4 = (float4*)cu;
        float4* __restrict__ cv4 = (float4*)cv;
        float4 u0 = cu4[2 * pl], u1 = cu4[2 * pl + 1];
        float4 v0 = cv4[2 * pl], v1 = cv4[2 * pl + 1];
        const float su = ((u0.x + u0.y) + (u0.z + u0.w)) + ((u1.x + u1.y) + (u1.z + u1.w));
        const float sv = ((v0.x + v0.y) + (v0.z + v0.w)) + ((v1.x + v1.y) + (v1.z + v1.w));
        float iu = su, iv = sv;
        #pragma unroll
        for (int off = 1; off < 64; off <<= 1) {
            const float a = __shfl_up(iu, off);
            const float b = __shfl_up(iv, off);
            if (lane >= off) { iu += a; iv += b; }
        }
        if (lane == 63) { psum[p][0][wl] = iu; psum[p][1][wl] = iv; }
        __syncthreads();
        float prefU = 0.f, totU = 0.f, prefV = 0.f, totV = 0.f;
        #pragma unroll
        for (int k = 0; k < 4; ++k) {
            const float a = psum[p][0][k], b = psum[p][1][k];
            totU += a; totV += b;
            if (k < wl) { prefU += a; prefV += b; }
        }
        const float invU = 1.0f / totU, invV = 1.0f / totV;
        float ru = prefU + (iu - su);
        float rv = prefV + (iv - sv);
        float4 o;
        ru += u0.x; o.x = ru * invU; ru += u0.y; o.y = ru * invU;
        ru += u0.z; o.z = ru * invU; ru += u0.w; o.w = ru * invU;
        cu4[2 * pl] = o;
        ru += u1.x; o.x = ru * invU; ru += u1.y; o.y = ru * invU;
        ru += u1.z; o.z = ru * invU; ru += u1.w; o.w = ru * invU;
        cu4[2 * pl + 1] = o;
        rv += v0.x; o.x = rv * invV; rv += v0.y; o.y = rv * invV;
        rv += v0.z; o.z = rv * invV; rv += v0.w; o.w = rv * invV;
        cv4[2 * pl] = o;
        rv += v1.x; o.x = rv * invV; rv += v1.y; o.y = rv * invV;
        rv += v1.z; o.z = rv * invV; rv += v1.w; o.w = rv * invV;
        cv4[2 * pl + 1] = o;
    }
    __syncthreads();

    // ---- co-rank partition, two segments per lane: dA=[16pl,+8), dB=[16pl+8,+8)
    // fixed 11 branchless levels; clamped reads hit sentinels / guarded updates.
    const int dA = pl << 4;
    const int dB = dA + 8;
    int loA = max(0, dA - T_N), hiA = min(dA, T_N);
    int loB = max(0, dB - T_N), hiB = min(dB, T_N);
    for (int it = 0; it < 11; ++it) {
        const int mA = (loA + hiA) >> 1;
        const int mB = (loB + hiB) >> 1;
        const float aA = cu[mA];
        const float bA = cv[max(dA - mA - 1, 0)];
        const float aB = cu[mB];
        const float bB = cv[max(dB - mB - 1, 0)];
        const bool gA = loA < hiA, gB = loB < hiB;
        const bool cA = gA && (aA <= bA);
        const bool cB = gB && (aB <= bB);
        loA = cA ? mA + 1 : loA;
        hiA = (gA && !cA) ? mA : hiA;
        loB = cB ? mB + 1 : loB;
        hiB = (gB && !cB) ? mB : hiB;
    }
    int iA = loA, jA = dA - loA;
    int iB = loB, jB = dB - loB;

    float qpA = 0.0f;
    if (dA > 0) {
        const float pa_ = (iA > 0) ? cu[iA - 1] : -INFV;
        const float pb_ = (jA > 0) ? cv[jA - 1] : -INFV;
        qpA = fmaxf(pa_, pb_);
    }
    float qpB;
    {
        const float pa_ = (iB > 0) ? cu[iB - 1] : -INFV;
        const float pb_ = (jB > 0) ? cv[jB - 1] : -INFV;
        qpB = fmaxf(pa_, pb_);
    }

    // ---- merge: 8 steps per segment, A/B interleaved, sentinel-based ----
    float uvA = cu[iA], vvA = cv[jA], puA = cu[iA + 1], pvA = cv[jA + 1];
    float uvB = cu[iB], vvB = cv[jB], puB = cu[iB + 1], pvB = cv[jB + 1];
    float accA = 0.0f, accB = 0.0f;
    #pragma unroll
    for (int s = 0; s < 8; ++s) {
        {
            const bool take = (uvA <= vvA);
            const float q = fminf(uvA, vvA);
            const float dd = (float)(min(iA, T_N - 1) - min(jA, T_N - 1));
            accA += (q - qpA) * dd * dd;
            qpA = q;
            iA += take ? 1 : 0;
            jA += take ? 0 : 1;
            uvA = take ? puA : uvA;
            vvA = take ? vvA : pvA;
            if (s < 7) { puA = cu[iA + 1]; pvA = cv[jA + 1]; }
        }
        {
            const bool take = (uvB <= vvB);
            const float q = fminf(uvB, vvB);
            const float dd = (float)(min(iB, T_N - 1) - min(jB, T_N - 1));
            accB += (q - qpB) * dd * dd;
            qpB = q;
            iB += take ? 1 : 0;
            jB += take ? 0 : 1;
            uvB = take ? puB : uvB;
            vvB = take ? vvB : pvB;
            if (s < 7) { puB = cu[iB + 1]; pvB = cv[jB + 1]; }
        }
    }
    float acc = accA + accB;

    // ---- reduce: wave -> LDS -> one atomic per block ----
    #pragma unroll
    for (int off = 32; off; off >>= 1) acc += __shfl_down(acc, off);
    if (lane == 0) pacc[p][wl] = acc;
    __syncthreads();
    if (tid == 0) {
        float r = 0.f;
        #pragma unroll
        for (int pp = 0; pp < 4; ++pp)
            r += (pacc[pp][0] + pacc[pp][1]) + (pacc[pp][2] + pacc[pp][3]);
        atomicAdd(&out[bs >> 3], r * (1.0f / ((float)T_N * (float)T_N)));
    }
}

extern "C" void kernel_launch(void* const* d_in, const int* in_sizes, int n_in,
                              void* d_out, int out_size, void* d_ws, size_t ws_size,
                              hipStream_t stream) {
    const float* x = (const float*)d_in[0];
    const float* y = (const float*)d_in[1];
    float* out = (float*)d_out;
    float* partial = (float*)d_ws;   // MIN_BLOCKS floats (8 KiB)

    kmin<<<MIN_BLOCKS, 256, 0, stream>>>(x, y, partial, out);
    kmain<<<SLICES * 64, 1024, 0, stream>>>(x, y, partial, out);
}

// Round 8
// 204.458 us; speedup vs baseline: 1.0860x; 1.0860x over previous
//
#include <hip/hip_runtime.h>

// Problem constants (from setup_inputs): B=4, S=8, T=2048, R=256
#define T_N 2048
#define R_N 256
#define SLICES 32                     // B*S
#define NELEM (SLICES * T_N * R_N)    // 16,777,216 per tensor
#define INFV 3.0e38f
#define MIN_BLOCKS 2048               // 2048 x 256 threads, 8 float4/tensor/thread
#define MIN_THREADS (MIN_BLOCKS * 256)
#define LSTR 2056                     // list stride: 2048 + 8 sentinel slots

// Word-level XOR bank swizzle: logical e -> physical e ^ ((e>>5)&31).
// Kills the structural stride-8-float (bank {0,8,16,24}) aliasing of the
// merge/corank access pattern: stride-8 and stride-1 lane patterns both land
// 2 lanes/bank (free, m136). Sentinels 2048..2055 map to themselves.
#define XS(e) ((e) ^ (((e) >> 5) & 31))

// Deep-ILP streaming min (unchanged: ~25us, HBM-bound).
__global__ __launch_bounds__(256) void kmin(const float* __restrict__ x,
                                            const float* __restrict__ y,
                                            float* __restrict__ partial,
                                            float* __restrict__ out) {
    if (blockIdx.x == 0 && threadIdx.x < 4) out[threadIdx.x] = 0.0f;
    const int g0 = blockIdx.x * 256 + threadIdx.x;   // 0..524287
    const float4* __restrict__ x4 = (const float4*)x;
    const float4* __restrict__ y4 = (const float4*)y;
    float m0 = INFV, m1 = INFV;
    #pragma unroll
    for (int half = 0; half < 2; ++half) {
        float4 va[4], vb[4];
        #pragma unroll
        for (int it = 0; it < 4; ++it) {
            const int idx = g0 + (half * 4 + it) * MIN_THREADS;
            va[it] = x4[idx];
            vb[it] = y4[idx];
        }
        #pragma unroll
        for (int it = 0; it < 4; ++it) {
            m0 = fminf(m0, fminf(fminf(va[it].x, va[it].y), fminf(va[it].z, va[it].w)));
            m1 = fminf(m1, fminf(fminf(vb[it].x, vb[it].y), fminf(vb[it].z, vb[it].w)));
        }
    }
    float m = fminf(m0, m1);
    #pragma unroll
    for (int off = 32; off; off >>= 1) m = fminf(m, __shfl_down(m, off));
    __shared__ float sm[4];
    if ((threadIdx.x & 63) == 0) sm[threadIdx.x >> 6] = m;
    __syncthreads();
    if (threadIdx.x == 0)
        partial[blockIdx.x] = fminf(fminf(sm[0], sm[1]), fminf(sm[2], sm[3]));
}

// 1024-thread block = 4 problems, 4 waves/problem (R6 structure, absmax 0.0),
// now with XOR bank swizzle + scalar swizzled scan + sentinel-direct merge.
__global__ __launch_bounds__(1024, 8) void kmain(const float* __restrict__ x,
                                                 const float* __restrict__ y,
                                                 const float* __restrict__ partial,
                                                 float* __restrict__ out) {
    __shared__ float L[8 * LSTR];     // problem p: U at (2p)*LSTR, V at (2p+1)*LSTR
    __shared__ float red16[16];
    __shared__ float psum[4][2][4];   // [problem][list][wave-chunk] scan partials
    __shared__ float pacc[4][4];      // [problem][wave] result partials

    const int tid = threadIdx.x;
    const int w = tid >> 6;           // wave 0..15
    const int lane = tid & 63;

    // ---- phase 0: global min (partial[2048], two elements per thread) ----
    {
        float m = fminf(partial[tid], partial[tid + 1024]);
        #pragma unroll
        for (int off = 32; off; off >>= 1) m = fminf(m, __shfl_down(m, off));
        if (lane == 0) red16[w] = m;
    }
    __syncthreads();
    float mn = red16[0];
    #pragma unroll
    for (int k = 1; k < 16; ++k) mn = fminf(mn, red16[k]);
    const float sh = 1.1f * fminf(mn, 0.0f);

    // ---- XCD-aware remap: 4 blocks sharing a 64B global line -> same XCD ----
    const int blk = blockIdx.x;
    const int xcd = blk & 7;
    const int k2 = blk >> 3;
    const int sub = k2 & 3;
    const int rest = k2 >> 2;
    const int rt = (((rest & 1) << 3) + xcd) * 4 + sub;   // 0..63
    const int bs = rest >> 1;                              // 0..31
    const size_t base = (size_t)bs * (T_N * R_N) + (size_t)(rt * 4);

    // ---- sentinels: logical 2048..2055 (swizzle-identity) = INF ----
    if (tid < 64) L[(tid >> 3) * LSTR + T_N + (tid & 7)] = INFV;

    // ---- staging: swizzled scalar writes (stride-1 pattern: 2/bank, free) ----
    #pragma unroll
    for (int it = 0; it < 2; ++it) {
        const int t = tid + 1024 * it;
        const int ts = XS(t);
        const float4 a = *(const float4*)(x + base + (size_t)t * R_N);
        const float4 b = *(const float4*)(y + base + (size_t)t * R_N);
        L[0 * LSTR + ts] = a.x - sh;  L[2 * LSTR + ts] = a.y - sh;
        L[4 * LSTR + ts] = a.z - sh;  L[6 * LSTR + ts] = a.w - sh;
        L[1 * LSTR + ts] = b.x - sh;  L[3 * LSTR + ts] = b.y - sh;
        L[5 * LSTR + ts] = b.z - sh;  L[7 * LSTR + ts] = b.w - sh;
    }
    __syncthreads();

    const int p  = w >> 2;            // problem 0..3
    const int wl = w & 3;             // wave within problem
    const int pl = (wl << 6) | lane;  // problem-lane 0..255
    float* __restrict__ cu = &L[(2 * p) * LSTR];
    float* __restrict__ cv = &L[(2 * p + 1) * LSTR];

    // ---- scan: lane owns logical [8*pl, 8*pl+8), scalar swizzled access ----
    {
        int off8[8];
        #pragma unroll
        for (int k = 0; k < 8; ++k) off8[k] = XS(8 * pl + k);
        float uu[8], vv8[8];
        float su = 0.f, sv = 0.f;
        #pragma unroll
        for (int k = 0; k < 8; ++k) { uu[k] = cu[off8[k]]; su += uu[k]; }
        #pragma unroll
        for (int k = 0; k < 8; ++k) { vv8[k] = cv[off8[k]]; sv += vv8[k]; }
        float iu = su, iv = sv;
        #pragma unroll
        for (int off = 1; off < 64; off <<= 1) {
            const float a = __shfl_up(iu, off);
            const float b = __shfl_up(iv, off);
            if (lane >= off) { iu += a; iv += b; }
        }
        if (lane == 63) { psum[p][0][wl] = iu; psum[p][1][wl] = iv; }
        __syncthreads();
        float prefU = 0.f, totU = 0.f, prefV = 0.f, totV = 0.f;
        #pragma unroll
        for (int k = 0; k < 4; ++k) {
            const float a = psum[p][0][k], b = psum[p][1][k];
            totU += a; totV += b;
            if (k < wl) { prefU += a; prefV += b; }
        }
        const float invU = 1.0f / totU, invV = 1.0f / totV;
        float ru = prefU + (iu - su);
        float rv = prefV + (iv - sv);
        #pragma unroll
        for (int k = 0; k < 8; ++k) { ru += uu[k];  cu[off8[k]] = ru * invU; }
        #pragma unroll
        for (int k = 0; k < 8; ++k) { rv += vv8[k]; cv[off8[k]] = rv * invV; }
    }
    __syncthreads();

    // ---- co-rank partition: lane handles merged window [16*pl, 16*pl+16) ----
    const int d = pl << 4;
    int i = 0, j = 0;
    if (d > 0) {
        int lo = (d > T_N) ? (d - T_N) : 0;
        int hi = (d < T_N) ? d : T_N;
        while (lo < hi) {
            const int mid = (lo + hi) >> 1;
            if (cu[XS(mid)] <= cv[XS(d - mid - 1)]) lo = mid + 1; else hi = mid;
        }
        i = lo; j = d - lo;
    }
    float qprev = 0.0f;
    if (d > 0) {
        const float pa_ = (i > 0) ? cu[XS(i - 1)] : -INFV;
        const float pb_ = (j > 0) ? cv[XS(j - 1)] : -INFV;
        qprev = fmaxf(pa_, pb_);
    }

    // ---- merge: 16 steps, refill only the advanced list, sentinel-direct ----
    float uv = cu[XS(i)];
    float vv = cv[XS(j)];
    float acc = 0.0f;
    #pragma unroll
    for (int s = 0; s < 16; ++s) {
        const bool take = (uv <= vv);
        const float q = fminf(uv, vv);
        const float dd = (float)(min(i, T_N - 1) - min(j, T_N - 1));
        acc += (q - qprev) * dd * dd;
        qprev = q;
        i += take ? 1 : 0;
        j += take ? 0 : 1;
        if (s < 15) {
            const int ni = take ? i : j;           // advanced index (<= 2048)
            const float* bp = take ? cu : cv;
            const float r = bp[XS(ni)];
            uv = take ? r : uv;
            vv = take ? vv : r;
        }
    }

    // ---- reduce: wave -> LDS -> one atomic per block ----
    #pragma unroll
    for (int off = 32; off; off >>= 1) acc += __shfl_down(acc, off);
    if (lane == 0) pacc[p][wl] = acc;
    __syncthreads();
    if (tid == 0) {
        float r = 0.f;
        #pragma unroll
        for (int pp = 0; pp < 4; ++pp)
            r += (pacc[pp][0] + pacc[pp][1]) + (pacc[pp][2] + pacc[pp][3]);
        atomicAdd(&out[bs >> 3], r * (1.0f / ((float)T_N * (float)T_N)));
    }
}

extern "C" void kernel_launch(void* const* d_in, const int* in_sizes, int n_in,
                              void* d_out, int out_size, void* d_ws, size_t ws_size,
                              hipStream_t stream) {
    const float* x = (const float*)d_in[0];
    const float* y = (const float*)d_in[1];
    float* out = (float*)d_out;
    float* partial = (float*)d_ws;   // MIN_BLOCKS floats (8 KiB)

    kmin<<<MIN_BLOCKS, 256, 0, stream>>>(x, y, partial, out);
    kmain<<<SLICES * 64, 1024, 0, stream>>>(x, y, partial, out);
}